// Round 1
// baseline (518.344 us; speedup 1.0000x reference)
//
#include <hip/hip_runtime.h>
#include <math.h>

#define FSTR 264   // f LDS row stride (shorts): 256 + 8 pad -> 528B, 16B-mult, bank shift 4
#define MSTR 136   // m LDS row stride (shorts): 128 + 8 pad -> 272B, 16B-mult, bank shift 4

typedef __attribute__((ext_vector_type(8))) short short8;
typedef __attribute__((ext_vector_type(4))) float f32x4;

__device__ __forceinline__ unsigned short f2bf(float x) {
    unsigned int u = __float_as_uint(x);
    u += 0x7fffu + ((u >> 16) & 1u);   // round-to-nearest-even
    return (unsigned short)(u >> 16);
}
__device__ __forceinline__ float fsilu(float x) {
    return x * (1.0f / (1.0f + __expf(-x)));
}
__device__ __forceinline__ float fsigm(float x) {
    return 1.0f / (1.0f + __expf(-x));
}
__device__ __forceinline__ void atomAddF(float* p, float v) {
    unsafeAtomicAdd(p, v);   // hardware global_atomic_add_f32 (device scope)
}

// ---------------------------------------------------------------------------
// Weight prep: transpose fp32 [K][128] -> bf16 [128][K] row-major.
// Layout pairs: (W1-like K=256, 32768 elems) then (W2-like K=128, 16384 elems),
// 5 pairs: ll_e, ll_c, kl_e, kl_c, node. Total 245760 elems.
// ---------------------------------------------------------------------------
struct PrepArgs { const float* src[10]; };

__global__ __launch_bounds__(256) void prep_weights(PrepArgs pa, short* __restrict__ wsb) {
    int idx = blockIdx.x * 256 + threadIdx.x;      // 0..245759, grid = 960
    int pair = idx / 49152;
    int rem  = idx - pair * 49152;
    int second = (rem >= 32768) ? 1 : 0;
    int mi = pair * 2 + second;
    int within = second ? (rem - 32768) : rem;
    int n, k, K;
    if (second) { K = 128; n = within >> 7; k = within & 127; }
    else        { K = 256; n = within >> 8; k = within & 255; }
    int dstoff = pair * 49152 + second * 32768;
    wsb[dstoff + n * K + k] = (short)f2bf(pa.src[mi][k * 128 + n]);
}

// ---------------------------------------------------------------------------
// Edge kernel: 64 edges/block, 256 threads (4 waves), wave w owns cols [32w,32w+32)
// mfma_f32_16x16x32_bf16: A[m=lane&15][k=quad*8+j], B[k=quad*8+j][n=lane&15],
// C/D[row=quad*4+r][col=lane&15]  (guide §3, HW-verified m89/m91)
// ---------------------------------------------------------------------------
__global__ __launch_bounds__(256) void edge_kernel(
    const float* __restrict__ hsrc_tab, const float* __restrict__ hdst_tab,
    const float* __restrict__ xsrc_tab, const float* __restrict__ xdst_tab,
    const int* __restrict__ esrc, const int* __restrict__ edst,
    const short* __restrict__ W1t, const float* __restrict__ b1v, const float* __restrict__ w256,
    const short* __restrict__ W2t, const float* __restrict__ b2v,
    const float* __restrict__ aW, const float* __restrict__ abv,
    const short* __restrict__ cW1t, const float* __restrict__ cb1v, const float* __restrict__ cw256,
    const short* __restrict__ cW2t, const float* __restrict__ cb2v, const float* __restrict__ cW3,
    float* __restrict__ hne, float* __restrict__ xne)
{
    __shared__ __align__(16) short f_lds[64 * FSTR];
    __shared__ __align__(16) short m_lds[64 * MSTR];
    __shared__ float dij_l[64];
    __shared__ float gate_l[64];
    __shared__ float xdf[3][64];
    __shared__ int   dstl[64];
    __shared__ float gp[4][64];

    const int t  = threadIdx.x;
    const int eb = blockIdx.x * 64;

    // ---- gather h_src/h_dst -> bf16 LDS (4 threads per edge, 32 cols each) ----
    {
        const int e = t >> 2, q = t & 3;
        const int eid = eb + e;
        const int s = esrc[eid], d = edst[eid];
        if (q == 0) dstl[e] = d;
        const float4* hs = (const float4*)(hsrc_tab + (size_t)s * 128 + q * 32);
        const float4* hd = (const float4*)(hdst_tab + (size_t)d * 128 + q * 32);
        short* frow = &f_lds[e * FSTR + q * 32];
#pragma unroll
        for (int i = 0; i < 8; i++) {
            float4 v = hs[i];
            *(ushort4*)(frow + i * 4) =
                make_ushort4(f2bf(v.x), f2bf(v.y), f2bf(v.z), f2bf(v.w));
        }
#pragma unroll
        for (int i = 0; i < 8; i++) {
            float4 v = hd[i];
            *(ushort4*)(frow + 128 + i * 4) =
                make_ushort4(f2bf(v.x), f2bf(v.y), f2bf(v.z), f2bf(v.w));
        }
    }
    if (t < 64) {
        const int eid = eb + t;
        const int s = esrc[eid], d = edst[eid];
        float dx = xsrc_tab[s * 3 + 0] - xdst_tab[d * 3 + 0];
        float dy = xsrc_tab[s * 3 + 1] - xdst_tab[d * 3 + 1];
        float dz = xsrc_tab[s * 3 + 2] - xdst_tab[d * 3 + 2];
        float dd = sqrtf(dx * dx + dy * dy + dz * dz);
        float inv = 1.0f / (dd + 1.0f);
        dij_l[t] = dd;
        xdf[0][t] = dx * inv; xdf[1][t] = dy * inv; xdf[2][t] = dz * inv;
    }
    __syncthreads();

    const int ln = t & 63, wv = t >> 6;
    const int lrow = ln & 15, quad = ln >> 4;
    const int c0 = wv * 32 + lrow, c1 = c0 + 16;

    // =================== h path ===================
    // GEMM1: m = silu(f @ eW1 + b1 + dij * eW1[256])
    {
        short8 bf0[8], bf1[8];
#pragma unroll
        for (int kt = 0; kt < 8; kt++) {
            bf0[kt] = *(const short8*)(W1t + c0 * 256 + kt * 32 + quad * 8);
            bf1[kt] = *(const short8*)(W1t + c1 * 256 + kt * 32 + quad * 8);
        }
        const float w0 = w256[c0], w1 = w256[c1];
        const float bb0 = b1v[c0], bb1 = b1v[c1];
#pragma unroll
        for (int mt = 0; mt < 4; mt++) {
            short8 af[8];
#pragma unroll
            for (int kt = 0; kt < 8; kt++)
                af[kt] = *(const short8*)(&f_lds[(mt * 16 + lrow) * FSTR + kt * 32 + quad * 8]);
            f32x4 a0 = {0.f, 0.f, 0.f, 0.f}, a1 = {0.f, 0.f, 0.f, 0.f};
#pragma unroll
            for (int kt = 0; kt < 8; kt++) {
                a0 = __builtin_amdgcn_mfma_f32_16x16x32_bf16(af[kt], bf0[kt], a0, 0, 0, 0);
                a1 = __builtin_amdgcn_mfma_f32_16x16x32_bf16(af[kt], bf1[kt], a1, 0, 0, 0);
            }
#pragma unroll
            for (int r = 0; r < 4; r++) {
                const int erow = mt * 16 + quad * 4 + r;
                const float dv = dij_l[erow];
                m_lds[erow * MSTR + c0] = (short)f2bf(fsilu(a0[r] + bb0 + dv * w0));
                m_lds[erow * MSTR + c1] = (short)f2bf(fsilu(a1[r] + bb1 + dv * w1));
            }
        }
    }
    __syncthreads();

    // GEMM2: m2 = silu(m @ eW2 + b2); gate partials via butterfly
    float m2s[4][8];
    {
        short8 bf0[4], bf1[4];
#pragma unroll
        for (int kt = 0; kt < 4; kt++) {
            bf0[kt] = *(const short8*)(W2t + c0 * 128 + kt * 32 + quad * 8);
            bf1[kt] = *(const short8*)(W2t + c1 * 128 + kt * 32 + quad * 8);
        }
        const float aw0 = aW[c0], aw1 = aW[c1];
        const float bb0 = b2v[c0], bb1 = b2v[c1];
#pragma unroll
        for (int mt = 0; mt < 4; mt++) {
            short8 af[4];
#pragma unroll
            for (int kt = 0; kt < 4; kt++)
                af[kt] = *(const short8*)(&m_lds[(mt * 16 + lrow) * MSTR + kt * 32 + quad * 8]);
            f32x4 a0 = {0.f, 0.f, 0.f, 0.f}, a1 = {0.f, 0.f, 0.f, 0.f};
#pragma unroll
            for (int kt = 0; kt < 4; kt++) {
                a0 = __builtin_amdgcn_mfma_f32_16x16x32_bf16(af[kt], bf0[kt], a0, 0, 0, 0);
                a1 = __builtin_amdgcn_mfma_f32_16x16x32_bf16(af[kt], bf1[kt], a1, 0, 0, 0);
            }
#pragma unroll
            for (int r = 0; r < 4; r++) {
                float v0 = fsilu(a0[r] + bb0);
                float v1 = fsilu(a1[r] + bb1);
                m2s[mt][r] = v0; m2s[mt][4 + r] = v1;
                float g = v0 * aw0 + v1 * aw1;
                g += __shfl_xor(g, 1, 64);
                g += __shfl_xor(g, 2, 64);
                g += __shfl_xor(g, 4, 64);
                g += __shfl_xor(g, 8, 64);
                if (lrow == 0) gp[wv][mt * 16 + quad * 4 + r] = g;
            }
        }
    }
    __syncthreads();
    if (t < 64) gate_l[t] = fsigm(gp[0][t] + gp[1][t] + gp[2][t] + gp[3][t] + abv[0]);
    __syncthreads();

    // msg_h scatter-add
#pragma unroll
    for (int mt = 0; mt < 4; mt++)
#pragma unroll
        for (int r = 0; r < 4; r++) {
            const int erow = mt * 16 + quad * 4 + r;
            const float gv = gate_l[erow];
            const size_t drow = (size_t)dstl[erow] * 128;
            atomAddF(&hne[drow + c0], m2s[mt][r] * gv);
            atomAddF(&hne[drow + c1], m2s[mt][4 + r] * gv);
        }

    // =================== x path ===================
    // GEMM1c: c = silu(f @ cW1 + cb1 + dij * cW1[256])  (overwrites m_lds)
    {
        short8 bf0[8], bf1[8];
#pragma unroll
        for (int kt = 0; kt < 8; kt++) {
            bf0[kt] = *(const short8*)(cW1t + c0 * 256 + kt * 32 + quad * 8);
            bf1[kt] = *(const short8*)(cW1t + c1 * 256 + kt * 32 + quad * 8);
        }
        const float w0 = cw256[c0], w1 = cw256[c1];
        const float bb0 = cb1v[c0], bb1 = cb1v[c1];
#pragma unroll
        for (int mt = 0; mt < 4; mt++) {
            short8 af[8];
#pragma unroll
            for (int kt = 0; kt < 8; kt++)
                af[kt] = *(const short8*)(&f_lds[(mt * 16 + lrow) * FSTR + kt * 32 + quad * 8]);
            f32x4 a0 = {0.f, 0.f, 0.f, 0.f}, a1 = {0.f, 0.f, 0.f, 0.f};
#pragma unroll
            for (int kt = 0; kt < 8; kt++) {
                a0 = __builtin_amdgcn_mfma_f32_16x16x32_bf16(af[kt], bf0[kt], a0, 0, 0, 0);
                a1 = __builtin_amdgcn_mfma_f32_16x16x32_bf16(af[kt], bf1[kt], a1, 0, 0, 0);
            }
#pragma unroll
            for (int r = 0; r < 4; r++) {
                const int erow = mt * 16 + quad * 4 + r;
                const float dv = dij_l[erow];
                m_lds[erow * MSTR + c0] = (short)f2bf(fsilu(a0[r] + bb0 + dv * w0));
                m_lds[erow * MSTR + c1] = (short)f2bf(fsilu(a1[r] + bb1 + dv * w1));
            }
        }
    }
    __syncthreads();

    // GEMM2c: c2 = silu(c @ cW2 + cb2); s = c2 @ cW3 (scalar per edge)
    {
        short8 bf0[4], bf1[4];
#pragma unroll
        for (int kt = 0; kt < 4; kt++) {
            bf0[kt] = *(const short8*)(cW2t + c0 * 128 + kt * 32 + quad * 8);
            bf1[kt] = *(const short8*)(cW2t + c1 * 128 + kt * 32 + quad * 8);
        }
        const float cw0 = cW3[c0], cw1 = cW3[c1];
        const float bb0 = cb2v[c0], bb1 = cb2v[c1];
#pragma unroll
        for (int mt = 0; mt < 4; mt++) {
            short8 af[4];
#pragma unroll
            for (int kt = 0; kt < 4; kt++)
                af[kt] = *(const short8*)(&m_lds[(mt * 16 + lrow) * MSTR + kt * 32 + quad * 8]);
            f32x4 a0 = {0.f, 0.f, 0.f, 0.f}, a1 = {0.f, 0.f, 0.f, 0.f};
#pragma unroll
            for (int kt = 0; kt < 4; kt++) {
                a0 = __builtin_amdgcn_mfma_f32_16x16x32_bf16(af[kt], bf0[kt], a0, 0, 0, 0);
                a1 = __builtin_amdgcn_mfma_f32_16x16x32_bf16(af[kt], bf1[kt], a1, 0, 0, 0);
            }
#pragma unroll
            for (int r = 0; r < 4; r++) {
                float v0 = fsilu(a0[r] + bb0);
                float v1 = fsilu(a1[r] + bb1);
                float g = v0 * cw0 + v1 * cw1;
                g += __shfl_xor(g, 1, 64);
                g += __shfl_xor(g, 2, 64);
                g += __shfl_xor(g, 4, 64);
                g += __shfl_xor(g, 8, 64);
                if (lrow == 0) gp[wv][mt * 16 + quad * 4 + r] = g;
            }
        }
    }
    __syncthreads();
    if (t < 64) {
        const float sv = gp[0][t] + gp[1][t] + gp[2][t] + gp[3][t];
        const int d = dstl[t];
        atomAddF(&xne[d * 3 + 0], sv * xdf[0][t]);
        atomAddF(&xne[d * 3 + 1], sv * xdf[1][t]);
        atomAddF(&xne[d * 3 + 2], sv * xdf[2][t]);
    }
}

// ---------------------------------------------------------------------------
// Node kernel: reads accumulators in d_out, overwrites with final outputs.
// nin = [h_lig, h_neigh/z]; h_out = h_lig + silu(nin@W1+b1)@W2 + b2
// ---------------------------------------------------------------------------
__global__ __launch_bounds__(256) void node_kernel(
    const float* __restrict__ h_lig, const float* __restrict__ zlig,
    const short* __restrict__ W1t, const float* __restrict__ b1v,
    const short* __restrict__ W2t, const float* __restrict__ b2v,
    const float* __restrict__ x_lig,
    float* __restrict__ acc_h, float* __restrict__ acc_x)
{
    __shared__ __align__(16) short f_lds[64 * FSTR];
    __shared__ __align__(16) short m_lds[64 * MSTR];
    const int t = threadIdx.x;
    const int nb = blockIdx.x * 64;

    {
        const int e = t >> 2, q = t & 3;
        const int node = nb + e;
        short* frow = &f_lds[e * FSTR + q * 32];
        if (node < 10000) {
            const float zi = 1.0f / zlig[node];
            const float4* hp = (const float4*)(h_lig + (size_t)node * 128 + q * 32);
            const float4* np = (const float4*)(acc_h + (size_t)node * 128 + q * 32);
#pragma unroll
            for (int i = 0; i < 8; i++) {
                float4 v = hp[i];
                *(ushort4*)(frow + i * 4) =
                    make_ushort4(f2bf(v.x), f2bf(v.y), f2bf(v.z), f2bf(v.w));
            }
#pragma unroll
            for (int i = 0; i < 8; i++) {
                float4 v = np[i];
                *(ushort4*)(frow + 128 + i * 4) =
                    make_ushort4(f2bf(v.x * zi), f2bf(v.y * zi), f2bf(v.z * zi), f2bf(v.w * zi));
            }
        } else {
            const ushort4 zz = make_ushort4(0, 0, 0, 0);
#pragma unroll
            for (int i = 0; i < 8; i++) {
                *(ushort4*)(frow + i * 4) = zz;
                *(ushort4*)(frow + 128 + i * 4) = zz;
            }
        }
    }
    __syncthreads();

    const int ln = t & 63, wv = t >> 6;
    const int lrow = ln & 15, quad = ln >> 4;
    const int c0 = wv * 32 + lrow, c1 = c0 + 16;

    {
        short8 bf0[8], bf1[8];
#pragma unroll
        for (int kt = 0; kt < 8; kt++) {
            bf0[kt] = *(const short8*)(W1t + c0 * 256 + kt * 32 + quad * 8);
            bf1[kt] = *(const short8*)(W1t + c1 * 256 + kt * 32 + quad * 8);
        }
        const float bb0 = b1v[c0], bb1 = b1v[c1];
#pragma unroll
        for (int mt = 0; mt < 4; mt++) {
            short8 af[8];
#pragma unroll
            for (int kt = 0; kt < 8; kt++)
                af[kt] = *(const short8*)(&f_lds[(mt * 16 + lrow) * FSTR + kt * 32 + quad * 8]);
            f32x4 a0 = {0.f, 0.f, 0.f, 0.f}, a1 = {0.f, 0.f, 0.f, 0.f};
#pragma unroll
            for (int kt = 0; kt < 8; kt++) {
                a0 = __builtin_amdgcn_mfma_f32_16x16x32_bf16(af[kt], bf0[kt], a0, 0, 0, 0);
                a1 = __builtin_amdgcn_mfma_f32_16x16x32_bf16(af[kt], bf1[kt], a1, 0, 0, 0);
            }
#pragma unroll
            for (int r = 0; r < 4; r++) {
                const int erow = mt * 16 + quad * 4 + r;
                m_lds[erow * MSTR + c0] = (short)f2bf(fsilu(a0[r] + bb0));
                m_lds[erow * MSTR + c1] = (short)f2bf(fsilu(a1[r] + bb1));
            }
        }
    }
    __syncthreads();

    {
        short8 bf0[4], bf1[4];
#pragma unroll
        for (int kt = 0; kt < 4; kt++) {
            bf0[kt] = *(const short8*)(W2t + c0 * 128 + kt * 32 + quad * 8);
            bf1[kt] = *(const short8*)(W2t + c1 * 128 + kt * 32 + quad * 8);
        }
        const float bb0 = b2v[c0], bb1 = b2v[c1];
#pragma unroll
        for (int mt = 0; mt < 4; mt++) {
            short8 af[4];
#pragma unroll
            for (int kt = 0; kt < 4; kt++)
                af[kt] = *(const short8*)(&m_lds[(mt * 16 + lrow) * MSTR + kt * 32 + quad * 8]);
            f32x4 a0 = {0.f, 0.f, 0.f, 0.f}, a1 = {0.f, 0.f, 0.f, 0.f};
#pragma unroll
            for (int kt = 0; kt < 4; kt++) {
                a0 = __builtin_amdgcn_mfma_f32_16x16x32_bf16(af[kt], bf0[kt], a0, 0, 0, 0);
                a1 = __builtin_amdgcn_mfma_f32_16x16x32_bf16(af[kt], bf1[kt], a1, 0, 0, 0);
            }
#pragma unroll
            for (int r = 0; r < 4; r++) {
                const int node = nb + mt * 16 + quad * 4 + r;
                if (node < 10000) {
                    acc_h[(size_t)node * 128 + c0] = a0[r] + bb0 + h_lig[(size_t)node * 128 + c0];
                    acc_h[(size_t)node * 128 + c1] = a1[r] + bb1 + h_lig[(size_t)node * 128 + c1];
                }
            }
        }
    }
    if (t < 64) {
        const int node = nb + t;
        if (node < 10000) {
            const float zi = 1.0f / zlig[node];
#pragma unroll
            for (int i = 0; i < 3; i++)
                acc_x[node * 3 + i] = x_lig[node * 3 + i] + acc_x[node * 3 + i] * zi;
        }
    }
}

extern "C" void kernel_launch(void* const* d_in, const int* in_sizes, int n_in,
                              void* d_out, int out_size, void* d_ws, size_t ws_size,
                              hipStream_t stream)
{
    (void)in_sizes; (void)n_in; (void)ws_size;
    const float* h_lig  = (const float*)d_in[0];
    const float* h_kp   = (const float*)d_in[1];
    const float* x_lig  = (const float*)d_in[2];
    const float* x_kp   = (const float*)d_in[3];
    const float* z_lig  = (const float*)d_in[4];
    const float* ll_eW1 = (const float*)d_in[5];
    const float* ll_eb1 = (const float*)d_in[6];
    const float* ll_eW2 = (const float*)d_in[7];
    const float* ll_eb2 = (const float*)d_in[8];
    const float* ll_aW  = (const float*)d_in[9];
    const float* ll_ab  = (const float*)d_in[10];
    const float* ll_cW1 = (const float*)d_in[11];
    const float* ll_cb1 = (const float*)d_in[12];
    const float* ll_cW2 = (const float*)d_in[13];
    const float* ll_cb2 = (const float*)d_in[14];
    const float* ll_cW3 = (const float*)d_in[15];
    const float* kl_eW1 = (const float*)d_in[16];
    const float* kl_eb1 = (const float*)d_in[17];
    const float* kl_eW2 = (const float*)d_in[18];
    const float* kl_eb2 = (const float*)d_in[19];
    const float* kl_aW  = (const float*)d_in[20];
    const float* kl_ab  = (const float*)d_in[21];
    const float* kl_cW1 = (const float*)d_in[22];
    const float* kl_cb1 = (const float*)d_in[23];
    const float* kl_cW2 = (const float*)d_in[24];
    const float* kl_cb2 = (const float*)d_in[25];
    const float* kl_cW3 = (const float*)d_in[26];
    const float* n_W1   = (const float*)d_in[27];
    const float* n_b1   = (const float*)d_in[28];
    const float* n_W2   = (const float*)d_in[29];
    const float* n_b2   = (const float*)d_in[30];
    const int* ll_src = (const int*)d_in[31];
    const int* ll_dst = (const int*)d_in[32];
    const int* kl_src = (const int*)d_in[33];
    const int* kl_dst = (const int*)d_in[34];

    float* out = (float*)d_out;
    float* hne = out;                 // [10000,128] h_neigh accum -> h_out
    float* xne = out + 1280000;       // [10000,3]  x_neigh accum -> x_out
    short* wsb = (short*)d_ws;        // 245760 bf16 = 480 KB of transposed weights

    hipMemsetAsync(d_out, 0, (size_t)out_size * sizeof(float), stream);

    PrepArgs pa;
    pa.src[0] = ll_eW1; pa.src[1] = ll_eW2; pa.src[2] = ll_cW1; pa.src[3] = ll_cW2;
    pa.src[4] = kl_eW1; pa.src[5] = kl_eW2; pa.src[6] = kl_cW1; pa.src[7] = kl_cW2;
    pa.src[8] = n_W1;   pa.src[9] = n_W2;
    prep_weights<<<960, 256, 0, stream>>>(pa, wsb);

    // ws layout (shorts): pair p at p*49152, W1-like first (32768), W2-like second (16384)
    edge_kernel<<<5000, 256, 0, stream>>>(
        h_lig, h_lig, x_lig, x_lig, ll_src, ll_dst,
        wsb + 0,      ll_eb1, ll_eW1 + 256 * 128,
        wsb + 32768,  ll_eb2, ll_aW, ll_ab,
        wsb + 49152,  ll_cb1, ll_cW1 + 256 * 128,
        wsb + 81920,  ll_cb2, ll_cW3,
        hne, xne);
    edge_kernel<<<2500, 256, 0, stream>>>(
        h_kp, h_lig, x_kp, x_lig, kl_src, kl_dst,
        wsb + 98304,  kl_eb1, kl_eW1 + 256 * 128,
        wsb + 131072, kl_eb2, kl_aW, kl_ab,
        wsb + 147456, kl_cb1, kl_cW1 + 256 * 128,
        wsb + 180224, kl_cb2, kl_cW3,
        hne, xne);

    node_kernel<<<157, 256, 0, stream>>>(
        h_lig, z_lig, wsb + 196608, n_b1, wsb + 229376, n_b2,
        x_lig, hne, xne);
}